// Round 6
// baseline (538.364 us; speedup 1.0000x reference)
//
#include <hip/hip_runtime.h>
#include <stdint.h>
#include <stddef.h>

#define NROWS 8192
#define NCOLS 8192       // K dimension = noise-matrix column count
#define DDIM  1024

typedef float  f32x4 __attribute__((ext_vector_type(4)));
typedef _Float16 f16x8 __attribute__((ext_vector_type(8)));

#if __has_builtin(__builtin_amdgcn_exp2f)
#define EXP2F(x) __builtin_amdgcn_exp2f(x)
#else
#define EXP2F(x) exp2f(x)
#endif
#if __has_builtin(__builtin_amdgcn_logf)
#define LOG2F(x) __builtin_amdgcn_logf(x)     // v_log_f32 = log2
#else
#define LOG2F(x) log2f(x)
#endif
#if __has_builtin(__builtin_amdgcn_sqrtf)
#define SQRTF(x) __builtin_amdgcn_sqrtf(x)
#else
#define SQRTF(x) sqrtf(x)
#endif

// ---------------- Threefry-2x32, key = (0, 42) (jax.random.key(42)) ---------
__device__ __forceinline__ uint32_t rotl32(uint32_t x, uint32_t r){
  return (x << r) | (x >> (32u - r));
}

__device__ __forceinline__ void threefry2x32(uint32_t x0, uint32_t x1,
                                             uint32_t& o0, uint32_t& o1){
  const uint32_t k0 = 0u, k1 = 42u;
  const uint32_t k2 = k0 ^ k1 ^ 0x1BD11BDAu;
  x0 += k0; x1 += k1;
#define TF_R(r) { x0 += x1; x1 = rotl32(x1, r); x1 ^= x0; }
  TF_R(13) TF_R(15) TF_R(26) TF_R(6)
  x0 += k1; x1 += k2 + 1u;
  TF_R(17) TF_R(29) TF_R(16) TF_R(24)
  x0 += k2; x1 += k0 + 2u;
  TF_R(13) TF_R(15) TF_R(26) TF_R(6)
  x0 += k0; x1 += k1 + 3u;
  TF_R(17) TF_R(29) TF_R(16) TF_R(24)
  x0 += k1; x1 += k2 + 4u;
  TF_R(13) TF_R(15) TF_R(26) TF_R(6)
  x0 += k2; x1 += k0 + 5u;
#undef TF_R
  o0 = x0; o1 = x1;
}

// Partitionable-threefry element: flat index f -> E' = exp(2*normal)*2^-4.
__device__ __forceinline__ float elemE(uint32_t f){
  uint32_t o0, o1;
  threefry2x32(0u, f, o0, o1);
  const uint32_t b = o0 ^ o1;
  float u = __uint_as_float((b >> 9) | 0x3F800000u) - 1.0f;   // [0,1)
  const float lo = -0.99999994f;                              // nextafter(-1,0)
  float v = fmaf(u, 2.0f, lo);
  v = fmaxf(v, lo);
  const float t1 = fmaf(-v, v, 1.0f);                         // 1 - v^2
  float w = LOG2F(t1) * (-0.69314718f);                       // -ln(1-v^2)
  float p;
  if (w < 5.0f){
    w -= 2.5f;
    p =              3.97426473e-08f;
    p = fmaf(p, w,   4.85465e-07f);
    p = fmaf(p, w,  -4.98283e-06f);
    p = fmaf(p, w,  -6.21053e-06f);
    p = fmaf(p, w,   3.09120e-04f);
    p = fmaf(p, w,  -1.77290e-03f);
    p = fmaf(p, w,  -5.90817e-03f);
    p = fmaf(p, w,   3.48803163e-01f);
    p = fmaf(p, w,   2.12331355e+00f);
  } else {
    w = SQRTF(w) - 3.0f;
    p =             -2.83147363e-04f;
    p = fmaf(p, w,   1.42765560e-04f);
    p = fmaf(p, w,   1.90825981e-03f);
    p = fmaf(p, w,  -5.19500608e-03f);
    p = fmaf(p, w,   8.11688602e-03f);
    p = fmaf(p, w,  -1.07798386e-02f);
    p = fmaf(p, w,   1.33487061e-02f);
    p = fmaf(p, w,   1.41658096e+00f);
    p = fmaf(p, w,   4.00643396e+00f);
  }
  const float m = p * v;                         // sqrt(2)*erfinv(v) ~ N(0,1)
  return EXP2F(fmaf(m, 2.8853900817779268f, -4.0f)); // exp(2m)*2^-4
}

__device__ __forceinline__ uint16_t f2h(float a){
  union { _Float16 h; uint16_t u; } c; c.h = (_Float16)a; return c.u;
}

// ---------------- transpose: x [8192][1024] f32 -> xT f16 -------------------
__global__ __launch_bounds__(256) void transpose_cast(const float* __restrict__ x,
                                                      uint16_t* __restrict__ xT){
  __shared__ float tile[32][33];
  const int tx = threadIdx.x & 31;
  const int ty = threadIdx.x >> 5;          // 0..7
  const int dcol = blockIdx.x * 32;
  const int nrow = blockIdx.y * 32;
  #pragma unroll
  for (int r = 0; r < 32; r += 8)
    tile[ty + r][tx] = x[(size_t)(nrow + ty + r) * DDIM + dcol + tx];
  __syncthreads();
  #pragma unroll
  for (int r = 0; r < 32; r += 8)
    xT[(size_t)(dcol + ty + r) * NROWS + nrow + tx] = f2h(tile[tx][ty + r]);
}

// ============= fused generate-in-GEMM v3 (no P materialization) =============
// Grid = 256 blocks x 1024 threads (16 waves, 4/SIMD). Block b owns output
// rows [32b,32b+32) x all 1024 cols; streams K in 256 steps of 32. Per step:
//  - gen: each thread computes 1 P element (threefry counter-based; P never
//    touches memory) into the 2 KB LDS A-tile (swizzled, conflict-free; v2's
//    verified layout). Row sums accumulate in-register (softmax denom).
//  - B: NO LDS. Each wave loads its own MFMA B-fragments directly from xT
//    with plain f16x8 global loads, double-buffered 2 STEPS AHEAD. The
//    compiler's auto-waitcnt gives a counted vmcnt wait (newer loads stay in
//    flight). No vmcnt drain anywhere in the main loop.
//  - barrier: raw s_barrier with lgkmcnt(0) only (A-tile visibility).
// This removes round 5's per-step vmcnt(0)-drain stall (the 55% idle time).
#define FM2 32
#define FK2 32
#define NST (NCOLS / FK2)    // 256 K-steps
#define A0_OFF 0
#define A1_OFF 2048

__global__ __launch_bounds__(1024, 4) void fused32v3(
    const uint16_t* __restrict__ xT,   // [1024][8192] f16
    float* __restrict__ O)             // [8192][1024] f32
{
  __shared__ uint8_t smb[4352];        // A0 (2KB) | A1 (2KB) | Ssum scratch

  const int t = threadIdx.x;
  const size_t m0 = (size_t)blockIdx.x * FM2;

  const int lane = t & 63;
  const int w    = t >> 6;             // 0..15; wave covers cols [64w, 64w+64)
  const int l15  = lane & 15;
  const int lq   = lane >> 4;          // 0..3 = k-granule of the MFMA frag

  // ---- gen mapping: thread t -> (row t>>5, k-col t&31), 1 element/step ----
  const int grow = t >> 5;             // 0..31
  const int gcol = t & 31;
  const uint32_t genbase = (uint32_t)(m0 + (size_t)grow) * 8192u + (uint32_t)gcol;
  const int a_sr = grow >> 1;
  const int a_g3 = (gcol >> 3) | ((grow & 1) << 2);
  const int aw_off = a_sr * 128 + (a_g3 ^ (a_sr & 7)) * 16 + (gcol & 7) * 2;

  // ---- A frag-read byte offsets (v2's verified conflict-free swizzle) ----
  const int fp = (lq | ((l15 & 1) << 2)) ^ ((l15 >> 1) & 7);
  int af_off[2];
  #pragma unroll
  for (int i = 0; i < 2; ++i)
    af_off[i] = (i * 8 + (l15 >> 1)) * 128 + fp * 16;

  // ---- B: per-lane direct global pointer. Frag f, step s reads 16B at
  // xT[(64w + 16f + l15)][s*32 + 8*lq] -- identical operand bytes to v2's
  // LDS-staged path (verified correct), just without the LDS round-trip.
  const uint16_t* bbase = xT + (size_t)(w * 64 + l15) * NCOLS + lq * 8;

  float myS = 0.0f;
  f32x4 acc[2][4];
  #pragma unroll
  for (int i = 0; i < 2; ++i)
    #pragma unroll
    for (int f = 0; f < 4; ++f)
      #pragma unroll
      for (int r = 0; r < 4; ++r) acc[i][f][r] = 0.0f;

  f16x8 bqA[4], bqB[4];                // statically-named step-parity buffers

#define LOADB(bq, s) {                                                        \
    const uint16_t* _p = bbase + (s) * FK2;                                   \
    _Pragma("unroll")                                                         \
    for (int f = 0; f < 4; ++f)                                               \
      bq[f] = *reinterpret_cast<const f16x8*>(_p + (size_t)f * 16 * NCOLS);   \
  }

#define GENA(abuf, s) {                                                       \
    const float _e = elemE(genbase + (uint32_t)((s) * FK2));                  \
    myS += _e;                                                                \
    *reinterpret_cast<_Float16*>(smb + (abuf) + aw_off) = (_Float16)_e;       \
  }

  // STEP: read A frags, gen next A, MFMA (compiler inserts counted vmcnt for
  // bq + lgkmcnt for af), reload bq for s+2, then lgkmcnt(0)+raw barrier.
#define STEP(ca, bq, na, s) {                                                 \
    f16x8 _af0 = *reinterpret_cast<const f16x8*>(smb + (ca) + af_off[0]);     \
    f16x8 _af1 = *reinterpret_cast<const f16x8*>(smb + (ca) + af_off[1]);     \
    if ((s) + 1 < NST) GENA(na, (s) + 1);                                     \
    __builtin_amdgcn_s_setprio(1);                                            \
    _Pragma("unroll")                                                         \
    for (int f = 0; f < 4; ++f)                                               \
      acc[0][f] = __builtin_amdgcn_mfma_f32_16x16x32_f16(_af0, bq[f], acc[0][f], 0, 0, 0); \
    _Pragma("unroll")                                                         \
    for (int f = 0; f < 4; ++f)                                               \
      acc[1][f] = __builtin_amdgcn_mfma_f32_16x16x32_f16(_af1, bq[f], acc[1][f], 0, 0, 0); \
    __builtin_amdgcn_s_setprio(0);                                            \
    if ((s) + 2 < NST) LOADB(bq, (s) + 2);                                    \
    asm volatile("s_waitcnt lgkmcnt(0)" ::: "memory");                        \
    __builtin_amdgcn_s_barrier();                                             \
  }

  // prologue: B for steps 0,1 in flight; A(0) generated and published.
  LOADB(bqA, 0);
  LOADB(bqB, 1);
  GENA(A0_OFF, 0);
  asm volatile("s_waitcnt lgkmcnt(0)" ::: "memory");
  __builtin_amdgcn_s_barrier();

  for (int s = 0; s < NST; s += 2){
    STEP(A0_OFF, bqA, A1_OFF, s);
    STEP(A1_OFF, bqB, A0_OFF, s + 1);
  }
#undef STEP
#undef GENA
#undef LOADB

  // ---- row sums -> softmax denominators. Lanes [0..31]/[32..63] of wave w
  // hold partials of rows 2w / 2w+1 (row = t>>5). Reduce within 32 lanes.
  float v = myS;
  v += __shfl_down(v, 16, 32);
  v += __shfl_down(v, 8, 32);
  v += __shfl_down(v, 4, 32);
  v += __shfl_down(v, 2, 32);
  v += __shfl_down(v, 1, 32);
  float* Ssum = reinterpret_cast<float*>(smb + 4224);  // past A buffers
  if ((lane & 31) == 0) Ssum[t >> 5] = v;
  __syncthreads();

  float rinv[2][4];
  #pragma unroll
  for (int i = 0; i < 2; ++i)
    #pragma unroll
    for (int r = 0; r < 4; ++r)
      rinv[i][r] = 1.0f / Ssum[i * 16 + lq * 4 + r];

  #pragma unroll
  for (int i = 0; i < 2; ++i)
    #pragma unroll
    for (int f = 0; f < 4; ++f){
      const size_t col = (size_t)w * 64 + f * 16 + l15;
      #pragma unroll
      for (int r = 0; r < 4; ++r){
        const size_t row = m0 + i * 16 + lq * 4 + r;  // C/D: col=lane&15, row=quad*4+reg
        __builtin_nontemporal_store(acc[i][f][r] * rinv[i][r], &O[row * DDIM + col]);
      }
    }
}

// ---------------------------------------------------------------------------
extern "C" void kernel_launch(void* const* d_in, const int* in_sizes, int n_in,
                              void* d_out, int out_size, void* d_ws, size_t ws_size,
                              hipStream_t stream)
{
  (void)in_sizes; (void)n_in; (void)out_size;
  const float* x = (const float*)d_in[0];       // [8192][1024] f32; d_in[1] unused
  float* O = (float*)d_out;                     // [8192][1024] f32
  uint8_t* ws = (uint8_t*)d_ws;

  // workspace: only xT (16.8 MB) -- P is never materialized.
  uint16_t* xT = (uint16_t*)ws;
  const size_t xT_bytes = (size_t)DDIM * NROWS * sizeof(uint16_t);
  if (ws_size < xT_bytes) return;               // cannot run without xT staging

  transpose_cast<<<dim3(DDIM/32, NROWS/32), 256, 0, stream>>>(x, xT);
  fused32v3<<<256, 1024, 0, stream>>>(xT, O);
}

// Round 7
// 463.044 us; speedup vs baseline: 1.1627x; 1.1627x over previous
//
#include <hip/hip_runtime.h>
#include <stdint.h>
#include <stddef.h>

#define NROWS 8192
#define NCOLS 8192       // K dimension = noise-matrix column count
#define DDIM  1024

typedef float  f32x4 __attribute__((ext_vector_type(4)));
typedef _Float16 f16x8 __attribute__((ext_vector_type(8)));

#if __has_builtin(__builtin_amdgcn_exp2f)
#define EXP2F(x) __builtin_amdgcn_exp2f(x)
#else
#define EXP2F(x) exp2f(x)
#endif
#if __has_builtin(__builtin_amdgcn_logf)
#define LOG2F(x) __builtin_amdgcn_logf(x)     // v_log_f32 = log2
#else
#define LOG2F(x) log2f(x)
#endif
#if __has_builtin(__builtin_amdgcn_sqrtf)
#define SQRTF(x) __builtin_amdgcn_sqrtf(x)
#else
#define SQRTF(x) sqrtf(x)
#endif

// ---------------- Threefry-2x32, key = (0, 42) (jax.random.key(42)) ---------
__device__ __forceinline__ uint32_t rotl32(uint32_t x, uint32_t r){
  return (x << r) | (x >> (32u - r));
}

__device__ __forceinline__ void threefry2x32(uint32_t x0, uint32_t x1,
                                             uint32_t& o0, uint32_t& o1){
  const uint32_t k0 = 0u, k1 = 42u;
  const uint32_t k2 = k0 ^ k1 ^ 0x1BD11BDAu;
  x0 += k0; x1 += k1;
#define TF_R(r) { x0 += x1; x1 = rotl32(x1, r); x1 ^= x0; }
  TF_R(13) TF_R(15) TF_R(26) TF_R(6)
  x0 += k1; x1 += k2 + 1u;
  TF_R(17) TF_R(29) TF_R(16) TF_R(24)
  x0 += k2; x1 += k0 + 2u;
  TF_R(13) TF_R(15) TF_R(26) TF_R(6)
  x0 += k0; x1 += k1 + 3u;
  TF_R(17) TF_R(29) TF_R(16) TF_R(24)
  x0 += k1; x1 += k2 + 4u;
  TF_R(13) TF_R(15) TF_R(26) TF_R(6)
  x0 += k2; x1 += k0 + 5u;
#undef TF_R
  o0 = x0; o1 = x1;
}

// Partitionable-threefry element: flat index f -> E' = exp(2*normal)*2^-4.
__device__ __forceinline__ float elemE(uint32_t f){
  uint32_t o0, o1;
  threefry2x32(0u, f, o0, o1);
  const uint32_t b = o0 ^ o1;
  float u = __uint_as_float((b >> 9) | 0x3F800000u) - 1.0f;   // [0,1)
  const float lo = -0.99999994f;                              // nextafter(-1,0)
  float v = fmaf(u, 2.0f, lo);
  v = fmaxf(v, lo);
  const float t1 = fmaf(-v, v, 1.0f);                         // 1 - v^2
  float w = LOG2F(t1) * (-0.69314718f);                       // -ln(1-v^2)
  float p;
  if (w < 5.0f){
    w -= 2.5f;
    p =              3.97426473e-08f;
    p = fmaf(p, w,   4.85465e-07f);
    p = fmaf(p, w,  -4.98283e-06f);
    p = fmaf(p, w,  -6.21053e-06f);
    p = fmaf(p, w,   3.09120e-04f);
    p = fmaf(p, w,  -1.77290e-03f);
    p = fmaf(p, w,  -5.90817e-03f);
    p = fmaf(p, w,   3.48803163e-01f);
    p = fmaf(p, w,   2.12331355e+00f);
  } else {
    w = SQRTF(w) - 3.0f;
    p =             -2.83147363e-04f;
    p = fmaf(p, w,   1.42765560e-04f);
    p = fmaf(p, w,   1.90825981e-03f);
    p = fmaf(p, w,  -5.19500608e-03f);
    p = fmaf(p, w,   8.11688602e-03f);
    p = fmaf(p, w,  -1.07798386e-02f);
    p = fmaf(p, w,   1.33487061e-02f);
    p = fmaf(p, w,   1.41658096e+00f);
    p = fmaf(p, w,   4.00643396e+00f);
  }
  const float m = p * v;                         // sqrt(2)*erfinv(v) ~ N(0,1)
  return EXP2F(fmaf(m, 2.8853900817779268f, -4.0f)); // exp(2m)*2^-4
}

__device__ __forceinline__ uint16_t f2h(float a){
  union { _Float16 h; uint16_t u; } c; c.h = (_Float16)a; return c.u;
}

// ---------------- transpose: x [8192][1024] f32 -> xT f16 -------------------
__global__ __launch_bounds__(256) void transpose_cast(const float* __restrict__ x,
                                                      uint16_t* __restrict__ xT){
  __shared__ float tile[32][33];
  const int tx = threadIdx.x & 31;
  const int ty = threadIdx.x >> 5;          // 0..7
  const int dcol = blockIdx.x * 32;
  const int nrow = blockIdx.y * 32;
  #pragma unroll
  for (int r = 0; r < 32; r += 8)
    tile[ty + r][tx] = x[(size_t)(nrow + ty + r) * DDIM + dcol + tx];
  __syncthreads();
  #pragma unroll
  for (int r = 0; r < 32; r += 8)
    xT[(size_t)(dcol + ty + r) * NROWS + nrow + tx] = f2h(tile[tx][ty + r]);
}

// ---------------- fallback gen (chunked workspace) --------------------------
__global__ __launch_bounds__(256) void gen_rows(uint16_t* __restrict__ P,
                                                float* __restrict__ S, int row0){
  const int gi = row0 + blockIdx.x;
  const uint32_t base = (uint32_t)gi * 8192u;
  const int t = threadIdx.x;
  uint16_t* __restrict__ prow = P + (size_t)blockIdx.x * NCOLS;
  float acc = 0.0f;
  #pragma unroll
  for (int g = 0; g < 4; ++g){
    const uint32_t j0 = (uint32_t)(g * 2048) + ((uint32_t)t << 3);
    float e[8];
    #pragma unroll
    for (int i = 0; i < 8; ++i){ e[i] = elemE(base + j0 + (uint32_t)i); acc += e[i]; }
    f16x8 pk;
    #pragma unroll
    for (int i = 0; i < 8; ++i) pk[i] = (_Float16)e[i];
    *reinterpret_cast<f16x8*>(prow + j0) = pk;
  }
  #pragma unroll
  for (int off = 32; off > 0; off >>= 1) acc += __shfl_down(acc, off, 64);
  __shared__ float sm[4];
  if ((t & 63) == 0) sm[t >> 6] = acc;
  __syncthreads();
  if (t == 0) S[gi] = (sm[0] + sm[1]) + (sm[2] + sm[3]);
}

typedef const __attribute__((address_space(1))) void GAS;
typedef __attribute__((address_space(3))) void LAS;

__device__ __forceinline__ void gload16(const void* g, void* l){
  __builtin_amdgcn_global_load_lds((GAS*)g, (LAS*)l, 16, 0, 0);
}

// ---------------- fallback GEMM (chunked path): 128x128, 1-phase ------------
#define BM 128
#define BN 128
#define BK 64

__global__ __launch_bounds__(256, 3) void gemm_rows(
    const uint16_t* __restrict__ P, const uint16_t* __restrict__ xT,
    const float* __restrict__ S, int row0, float* __restrict__ O)
{
  __shared__ uint16_t smem[16384];      // As[128][64] | Bs[128][64]
  uint16_t* As = smem;
  uint16_t* Bs = smem + 8192;

  const int tid  = threadIdx.x;
  const int lane = tid & 63;
  const int wave = tid >> 6;
  const int wr = (wave >> 1) * 64;
  const int wc = (wave & 1) * 64;
  const int l15 = lane & 15;
  const int lq  = lane >> 4;

  const size_t m0 = (size_t)blockIdx.x * BM;
  const size_t n0 = (size_t)blockIdx.y * BN;

  const int srow = tid >> 3;                    // 0..31
  const int sx   = (tid & 7) ^ (srow & 7);      // swizzled source k-group
  const uint16_t* gA = P  + (m0 + srow) * (size_t)NCOLS + sx * 8;
  const uint16_t* gB = xT + (n0 + srow) * (size_t)NCOLS + sx * 8;

  f32x4 acc[4][4];
  #pragma unroll
  for (int i = 0; i < 4; ++i)
    #pragma unroll
    for (int j = 0; j < 4; ++j)
      #pragma unroll
      for (int q = 0; q < 4; ++q) acc[i][j][q] = 0.0f;

  const int axor = l15 & 7;

  for (int k0 = 0; k0 < NCOLS; k0 += BK){
    #pragma unroll
    for (int r = 0; r < 4; ++r)
      gload16(gA + (size_t)(32 * r) * NCOLS + k0, As + (tid + 256 * r) * 8);
    #pragma unroll
    for (int r = 0; r < 4; ++r)
      gload16(gB + (size_t)(32 * r) * NCOLS + k0, Bs + (tid + 256 * r) * 8);
    __syncthreads();
    #pragma unroll
    for (int ks = 0; ks < 2; ++ks){
      const int kphys = ((lq + 4 * ks) ^ axor) * 8;
      f16x8 af[4], bfrag[4];
      #pragma unroll
      for (int i = 0; i < 4; ++i)
        af[i] = *reinterpret_cast<const f16x8*>(As + (wr + i*16 + l15) * BK + kphys);
      #pragma unroll
      for (int j = 0; j < 4; ++j)
        bfrag[j] = *reinterpret_cast<const f16x8*>(Bs + (wc + j*16 + l15) * BK + kphys);
      #pragma unroll
      for (int i = 0; i < 4; ++i)
        #pragma unroll
        for (int j = 0; j < 4; ++j)
          acc[i][j] = __builtin_amdgcn_mfma_f32_16x16x32_f16(af[i], bfrag[j], acc[i][j], 0, 0, 0);
    }
    __syncthreads();
  }

  #pragma unroll
  for (int i = 0; i < 4; ++i){
    float rinv[4];
    #pragma unroll
    for (int r = 0; r < 4; ++r)
      rinv[r] = 1.0f / S[row0 + m0 + wr + i*16 + lq*4 + r];
    #pragma unroll
    for (int j = 0; j < 4; ++j){
      const size_t col = n0 + wc + j*16 + l15;
      #pragma unroll
      for (int r = 0; r < 4; ++r){
        const size_t row = m0 + wr + i*16 + lq*4 + r;
        O[row * DDIM + col] = acc[i][j][r] * rinv[r];
      }
    }
  }
}

// ================== PHASED persistent gen+GEMM kernel =======================
// One kernel, 256 blocks x 512 thr, 144 KB LDS -> exactly 1 block/CU, all 256
// co-resident (deadlock-free by capacity). K split into 8 chunks of 1024.
// Phase c: every block runs 16 K-tiles of the VERIFIED round-1 gemm256 loop
// on chunk c (acc persists in registers across phases -- same kernel), with
// 4 elemE generated per K-tile iteration producing chunk c+1 (gen VALU fills
// the gemm's stall time; MFMA+VALU are separate pipes, m114). P chunk writes:
// sc1 relaxed agent atomic b64 stores (write-through to IC; consumers
// first-touch the lines next phase => coherent, round-3-proven). Between
// phases: ONE relaxed-spin grid barrier on a single counter (8 total).
#define PM 256
#define PN 128
#define PK 64
#define TPC 16                 // k-tiles per chunk (chunk = 1024 cols)
#define NCH 8                  // chunks
#define PGBUF 24576            // uint16 elems per LDS buffer (A 16384 + B 8192)

__global__ __launch_bounds__(512, 2) void phased(
    uint16_t* __restrict__ P,          // [8192][8192] f16 (written chunkwise)
    const uint16_t* __restrict__ xT,   // [1024][8192] f16
    float* S,                          // [8192] row sums (sc1 stores/loads)
    uint32_t* ctr,                     // grid barrier counter (zeroed by host)
    float* __restrict__ O)             // [8192][1024] f32
{
  extern __shared__ uint16_t sm[];     // 3 * PGBUF = 144 KB
  const int tid = threadIdx.x;
  const int b   = blockIdx.x;

  // ---- gemm tile mapping (round-1 verified XCD swizzle) ----
  const int swz = (b & 7) * 32 + (b >> 3);
  const size_t m0 = (size_t)(swz & 31) * PM;    // 32 m-tiles
  const size_t n0 = (size_t)(swz >> 5) * PN;    // 8  n-tiles

  const int lane = tid & 63;
  const int wave = tid >> 6;           // 0..7
  const int wr = (wave >> 1) * 64;
  const int wc = (wave & 1) * 64;
  const int l15 = lane & 15;
  const int lq  = lane >> 4;
  const int axor = l15 & 7;

  const int srow = tid >> 3;           // 0..63
  const int sx   = (tid & 7) ^ (srow & 7);
  const uint16_t* gA = P  + (m0 + srow) * (size_t)NCOLS + sx * 8;
  const uint16_t* gB = xT + (n0 + srow) * (size_t)NCOLS + sx * 8;

  uint16_t* buf0 = sm;
  uint16_t* buf1 = sm + PGBUF;
  uint16_t* buf2 = sm + 2 * PGBUF;

  // ---- gen mapping: block b owns rows [32b,32b+32); thread t -> row t>>4,
  // 4 cols per K-tile iter at col chunk*1024 + kt*64 + (t&15)*4. Lanes 0-15
  // write 8B contiguous -> 128B segments. ----
  const int grow = tid >> 4;           // 0..31
  const int gl   = tid & 15;
  const uint32_t growg = (uint32_t)(b * 32 + grow);
  uint16_t* prow = P + (size_t)growg * NCOLS + gl * 4;
  const uint32_t fbase = growg * 8192u + (uint32_t)(gl * 4);
  float myS = 0.0f;

  auto GEN4 = [&](int chunk, int kt){
    const uint32_t f0 = fbase + (uint32_t)(chunk * 1024 + kt * 64);
    float e0 = elemE(f0), e1 = elemE(f0 + 1u), e2 = elemE(f0 + 2u), e3 = elemE(f0 + 3u);
    myS += (e0 + e1) + (e2 + e3);
    union { _Float16 h[4]; uint64_t u; } pk;
    pk.h[0] = (_Float16)e0; pk.h[1] = (_Float16)e1;
    pk.h[2] = (_Float16)e2; pk.h[3] = (_Float16)e3;
    __hip_atomic_store(reinterpret_cast<uint64_t*>(prow + chunk * 1024 + kt * 64),
                       pk.u, __ATOMIC_RELAXED, __HIP_MEMORY_SCOPE_AGENT);
  };

  auto STAGE = [&](uint16_t* base, int kt){
    const int kk = kt * PK;
    #pragma unroll
    for (int r = 0; r < 4; ++r)
      gload16(gA + (size_t)(64 * r) * NCOLS + kk, base + (tid + 512 * r) * 8);
    #pragma unroll
    for (int r = 0; r < 2; ++r)
      gload16(gB + (size_t)(64 * r) * NCOLS + kk, base + 16384 + (tid + 512 * r) * 8);
  };

  // grid barrier: drain, block-barrier, t0 arrives + relaxed-spins, release.
  auto phase_sync = [&](uint32_t target){
    asm volatile("s_waitcnt vmcnt(0) lgkmcnt(0)" ::: "memory");
    __builtin_amdgcn_s_barrier();
    if (tid == 0){
      __hip_atomic_fetch_add(ctr, 1u, __ATOMIC_RELAXED, __HIP_MEMORY_SCOPE_AGENT);
      int guard = 0;
      while (__hip_atomic_load(ctr, __ATOMIC_RELAXED, __HIP_MEMORY_SCOPE_AGENT) < target){
        __builtin_amdgcn_s_sleep(2);
        if (++guard > (1 << 22)) break;   // safety valve; never hit if correct
      }
    }
    __builtin_amdgcn_s_barrier();
  };

  f32x4 acc[4][4];
  #pragma unroll
  for (int i = 0; i < 4; ++i)
    #pragma unroll
    for (int j = 0; j < 4; ++j)
      #pragma unroll
      for (int q = 0; q < 4; ++q) acc[i][j][q] = 0.0f;

  // ---- init phase: generate chunk 0 (64 elemE/thread) ----
  for (int kt = 0; kt < TPC; ++kt) GEN4(0, kt);
  phase_sync(256);

  // ---- 8 phases: gemm chunk c (verified 16-tile loop) + gen chunk c+1 ----
  for (int c = 0; c < NCH; ++c){
    const int kb = c * TPC;
    const bool gen = (c + 1 < NCH);

    STAGE(buf0, kb);
    STAGE(buf1, kb + 1);
    asm volatile("s_waitcnt vmcnt(6)" ::: "memory");
    __builtin_amdgcn_s_barrier();

    uint16_t *pc = buf0, *pn = buf1, *ps = buf2;
    for (int t2 = 0; t2 < TPC; ++t2){
      if (t2 + 2 < TPC) STAGE(ps, kb + t2 + 2);
      if (gen) GEN4(c + 1, t2);      // 4 elemE: VALU fills gemm stall time

      #pragma unroll
      for (int ks = 0; ks < 2; ++ks){
        const int kphys = ((lq + 4 * ks) ^ axor) * 8;
        f16x8 af[4], bfrag[4];
        #pragma unroll
        for (int i = 0; i < 4; ++i)
          af[i] = *reinterpret_cast<const f16x8*>(pc + (wr + i*16 + l15) * PK + kphys);
        #pragma unroll
        for (int j = 0; j < 4; ++j)
          bfrag[j] = *reinterpret_cast<const f16x8*>(pc + 16384 + (wc + j*16 + l15) * PK + kphys);
        __builtin_amdgcn_s_setprio(1);
        #pragma unroll
        for (int i = 0; i < 4; ++i)
          #pragma unroll
          for (int j = 0; j < 4; ++j)
            acc[i][j] = __builtin_amdgcn_mfma_f32_16x16x32_f16(af[i], bfrag[j], acc[i][j], 0, 0, 0);
        __builtin_amdgcn_s_setprio(0);
      }

      // counted wait: tile t2+1's 6 loads done; tile t2+2's 6 (+1 gen store)
      // stay in flight. In-order vmcnt: queue = st(t+1):6, st(t+2):6 [,store:1].
      if (t2 + 2 < TPC){
        if (gen) asm volatile("s_waitcnt vmcnt(7) lgkmcnt(0)" ::: "memory");
        else     asm volatile("s_waitcnt vmcnt(6) lgkmcnt(0)" ::: "memory");
      } else {
        asm volatile("s_waitcnt vmcnt(0) lgkmcnt(0)" ::: "memory");
      }
      __builtin_amdgcn_s_barrier();
      uint16_t* tmp = pc; pc = pn; pn = ps; ps = tmp;
    }

    if (c == NCH - 2){
      // all gen done (chunk 7 written this phase): publish row sums once.
      float v = myS;
      v += __shfl_down(v, 8, 16);
      v += __shfl_down(v, 4, 16);
      v += __shfl_down(v, 2, 16);
      v += __shfl_down(v, 1, 16);
      if (gl == 0)
        __hip_atomic_store(&S[growg], v, __ATOMIC_RELAXED, __HIP_MEMORY_SCOPE_AGENT);
    }
    if (c + 1 < NCH) phase_sync(256u * (uint32_t)(c + 2));
  }

  // ---- epilogue: normalize by row sums (complete since phase-7 barrier) ----
  #pragma unroll
  for (int i = 0; i < 4; ++i){
    float rinv[4];
    #pragma unroll
    for (int r = 0; r < 4; ++r){
      const float sv = __hip_atomic_load(&S[m0 + wr + i*16 + lq*4 + r],
                                         __ATOMIC_RELAXED, __HIP_MEMORY_SCOPE_AGENT);
      rinv[r] = 1.0f / sv;
    }
    #pragma unroll
    for (int j = 0; j < 4; ++j){
      const size_t col = n0 + wc + j*16 + l15;
      #pragma unroll
      for (int r = 0; r < 4; ++r){
        const size_t row = m0 + wr + i*16 + lq*4 + r;  // C/D: col=lane&15, row=quad*4+reg
        __builtin_nontemporal_store(acc[i][j][r] * rinv[r], &O[row * DDIM + col]);
      }
    }
  }
}

// ---------------------------------------------------------------------------
extern "C" void kernel_launch(void* const* d_in, const int* in_sizes, int n_in,
                              void* d_out, int out_size, void* d_ws, size_t ws_size,
                              hipStream_t stream)
{
  (void)in_sizes; (void)n_in; (void)out_size;
  const float* x = (const float*)d_in[0];       // [8192][1024] f32; d_in[1] unused
  float* O = (float*)d_out;                     // [8192][1024] f32
  uint8_t* ws = (uint8_t*)d_ws;

  // layout: S[8192] f32 (32KB) | ctr (4KB pad) | xT (16.8MB) | P (134MB)
  float* S = (float*)ws;
  uint32_t* ctr = (uint32_t*)(ws + 32768);
  uint16_t* xT = (uint16_t*)(ws + 32768 + 4096);
  const size_t xT_bytes = (size_t)DDIM * NROWS * sizeof(uint16_t);
  uint16_t* P = (uint16_t*)(ws + 32768 + 4096 + xT_bytes);
  const size_t used = 32768 + 4096 + xT_bytes;
  const size_t avail = ws_size > used ? ws_size - used : 0;

  const size_t fullP = (size_t)NROWS * NCOLS * sizeof(uint16_t);       // 134 MB
  if (avail >= fullP){
    hipMemsetAsync(ctr, 0, 4096, stream);
    transpose_cast<<<dim3(DDIM/32, NROWS/32), 256, 0, stream>>>(x, xT);
    phased<<<256, 512, 3 * PGBUF * sizeof(uint16_t), stream>>>(P, xT, S, ctr, O);
  } else {
    transpose_cast<<<dim3(DDIM/32, NROWS/32), 256, 0, stream>>>(x, xT);
    int R = 128;
    for (int r = 4096; r >= 128; r >>= 1)
      if ((size_t)r * NCOLS * sizeof(uint16_t) <= avail){ R = r; break; }
    for (int r0 = 0; r0 < NROWS; r0 += R){
      gen_rows<<<R, 256, 0, stream>>>(P, S, r0);
      gemm_rows<<<dim3(R/BM, DDIM/BN), 256, 0, stream>>>(P, xT, S, r0, O + (size_t)r0 * DDIM);
    }
  }
}

// Round 8
// 356.865 us; speedup vs baseline: 1.5086x; 1.2975x over previous
//
#include <hip/hip_runtime.h>
#include <stdint.h>
#include <stddef.h>

#define NROWS 8192
#define NCOLS 8192       // K dimension = noise-matrix column count
#define DDIM  1024

typedef float  f32x4 __attribute__((ext_vector_type(4)));
typedef _Float16 f16x8 __attribute__((ext_vector_type(8)));

#if __has_builtin(__builtin_amdgcn_exp2f)
#define EXP2F(x) __builtin_amdgcn_exp2f(x)
#else
#define EXP2F(x) exp2f(x)
#endif
#if __has_builtin(__builtin_amdgcn_logf)
#define LOG2F(x) __builtin_amdgcn_logf(x)     // v_log_f32 = log2
#else
#define LOG2F(x) log2f(x)
#endif
#if __has_builtin(__builtin_amdgcn_sqrtf)
#define SQRTF(x) __builtin_amdgcn_sqrtf(x)
#else
#define SQRTF(x) sqrtf(x)
#endif

// ---------------- Threefry-2x32, key = (0, 42) (jax.random.key(42)) ---------
__device__ __forceinline__ uint32_t rotl32(uint32_t x, uint32_t r){
  return (x << r) | (x >> (32u - r));
}

__device__ __forceinline__ void threefry2x32(uint32_t x0, uint32_t x1,
                                             uint32_t& o0, uint32_t& o1){
  const uint32_t k0 = 0u, k1 = 42u;
  const uint32_t k2 = k0 ^ k1 ^ 0x1BD11BDAu;
  x0 += k0; x1 += k1;
#define TF_R(r) { x0 += x1; x1 = rotl32(x1, r); x1 ^= x0; }
  TF_R(13) TF_R(15) TF_R(26) TF_R(6)
  x0 += k1; x1 += k2 + 1u;
  TF_R(17) TF_R(29) TF_R(16) TF_R(24)
  x0 += k2; x1 += k0 + 2u;
  TF_R(13) TF_R(15) TF_R(26) TF_R(6)
  x0 += k0; x1 += k1 + 3u;
  TF_R(17) TF_R(29) TF_R(16) TF_R(24)
  x0 += k1; x1 += k2 + 4u;
  TF_R(13) TF_R(15) TF_R(26) TF_R(6)
  x0 += k2; x1 += k0 + 5u;
#undef TF_R
  o0 = x0; o1 = x1;
}

// Partitionable-threefry element: flat index f -> E' = exp(2*normal)*2^-4.
__device__ __forceinline__ float elemE(uint32_t f){
  uint32_t o0, o1;
  threefry2x32(0u, f, o0, o1);
  const uint32_t b = o0 ^ o1;
  float u = __uint_as_float((b >> 9) | 0x3F800000u) - 1.0f;   // [0,1)
  const float lo = -0.99999994f;                              // nextafter(-1,0)
  float v = fmaf(u, 2.0f, lo);
  v = fmaxf(v, lo);
  const float t1 = fmaf(-v, v, 1.0f);                         // 1 - v^2
  float w = LOG2F(t1) * (-0.69314718f);                       // -ln(1-v^2)
  float p;
  if (w < 5.0f){
    w -= 2.5f;
    p =              3.97426473e-08f;
    p = fmaf(p, w,   4.85465e-07f);
    p = fmaf(p, w,  -4.98283e-06f);
    p = fmaf(p, w,  -6.21053e-06f);
    p = fmaf(p, w,   3.09120e-04f);
    p = fmaf(p, w,  -1.77290e-03f);
    p = fmaf(p, w,  -5.90817e-03f);
    p = fmaf(p, w,   3.48803163e-01f);
    p = fmaf(p, w,   2.12331355e+00f);
  } else {
    w = SQRTF(w) - 3.0f;
    p =             -2.83147363e-04f;
    p = fmaf(p, w,   1.42765560e-04f);
    p = fmaf(p, w,   1.90825981e-03f);
    p = fmaf(p, w,  -5.19500608e-03f);
    p = fmaf(p, w,   8.11688602e-03f);
    p = fmaf(p, w,  -1.07798386e-02f);
    p = fmaf(p, w,   1.33487061e-02f);
    p = fmaf(p, w,   1.41658096e+00f);
    p = fmaf(p, w,   4.00643396e+00f);
  }
  const float m = p * v;                         // sqrt(2)*erfinv(v) ~ N(0,1)
  return EXP2F(fmaf(m, 2.8853900817779268f, -4.0f)); // exp(2m)*2^-4
}

__device__ __forceinline__ uint16_t f2h(float a){
  union { _Float16 h; uint16_t u; } c; c.h = (_Float16)a; return c.u;
}

// ---------------- fallback transpose: x [8192][1024] f32 -> xT f16 ----------
__global__ __launch_bounds__(256) void transpose_cast(const float* __restrict__ x,
                                                      uint16_t* __restrict__ xT){
  __shared__ float tile[32][33];
  const int tx = threadIdx.x & 31;
  const int ty = threadIdx.x >> 5;          // 0..7
  const int dcol = blockIdx.x * 32;
  const int nrow = blockIdx.y * 32;
  #pragma unroll
  for (int r = 0; r < 32; r += 8)
    tile[ty + r][tx] = x[(size_t)(nrow + ty + r) * DDIM + dcol + tx];
  __syncthreads();
  #pragma unroll
  for (int r = 0; r < 32; r += 8)
    xT[(size_t)(dcol + ty + r) * NROWS + nrow + tx] = f2h(tile[tx][ty + r]);
}

// ---------------- full path: transpose tile + gen row, one dispatch ---------
// (round-0 verified, 151 us, VALU-bound) Block b: transposes one 32x32 x-tile
// into xT and generates P row b (E' = exp(2m)*2^-4, f16) + row sum S[b].
__global__ __launch_bounds__(256) void gen_trans_rows(const float* __restrict__ x,
                                                      uint16_t* __restrict__ xT,
                                                      uint16_t* __restrict__ P,
                                                      float* __restrict__ S){
  const int t = threadIdx.x;
  {
    __shared__ float tile[32][33];
    const int tx = t & 31;
    const int ty = t >> 5;                  // 0..7
    const int dcol = (blockIdx.x & 31) * 32;
    const int nrow = (blockIdx.x >> 5) * 32;
    #pragma unroll
    for (int r = 0; r < 32; r += 8)
      tile[ty + r][tx] = x[(size_t)(nrow + ty + r) * DDIM + dcol + tx];
    __syncthreads();
    #pragma unroll
    for (int r = 0; r < 32; r += 8)
      xT[(size_t)(dcol + ty + r) * NROWS + nrow + tx] = f2h(tile[tx][ty + r]);
  }
  const int gi = blockIdx.x;
  const uint32_t base = (uint32_t)gi * 8192u;
  uint16_t* __restrict__ prow = P + (size_t)gi * NCOLS;
  float acc = 0.0f;
  #pragma unroll
  for (int g = 0; g < 4; ++g){
    const uint32_t j0 = (uint32_t)(g * 2048) + ((uint32_t)t << 3);
    float e[8];
    #pragma unroll
    for (int i = 0; i < 8; ++i){ e[i] = elemE(base + j0 + (uint32_t)i); acc += e[i]; }
    f16x8 pk;
    #pragma unroll
    for (int i = 0; i < 8; ++i) pk[i] = (_Float16)e[i];
    *reinterpret_cast<f16x8*>(prow + j0) = pk;    // 16B coalesced store
  }
  #pragma unroll
  for (int off = 32; off > 0; off >>= 1) acc += __shfl_down(acc, off, 64);
  __shared__ float sm[4];
  __syncthreads();
  if ((t & 63) == 0) sm[t >> 6] = acc;
  __syncthreads();
  if (t == 0) S[gi] = (sm[0] + sm[1]) + (sm[2] + sm[3]);
}

// ---------------- fallback gen (chunked workspace) --------------------------
__global__ __launch_bounds__(256) void gen_rows(uint16_t* __restrict__ P,
                                                float* __restrict__ S, int row0){
  const int gi = row0 + blockIdx.x;
  const uint32_t base = (uint32_t)gi * 8192u;
  const int t = threadIdx.x;
  uint16_t* __restrict__ prow = P + (size_t)blockIdx.x * NCOLS;
  float acc = 0.0f;
  #pragma unroll
  for (int g = 0; g < 4; ++g){
    const uint32_t j0 = (uint32_t)(g * 2048) + ((uint32_t)t << 3);
    float e[8];
    #pragma unroll
    for (int i = 0; i < 8; ++i){ e[i] = elemE(base + j0 + (uint32_t)i); acc += e[i]; }
    f16x8 pk;
    #pragma unroll
    for (int i = 0; i < 8; ++i) pk[i] = (_Float16)e[i];
    *reinterpret_cast<f16x8*>(prow + j0) = pk;
  }
  #pragma unroll
  for (int off = 32; off > 0; off >>= 1) acc += __shfl_down(acc, off, 64);
  __shared__ float sm[4];
  if ((t & 63) == 0) sm[t >> 6] = acc;
  __syncthreads();
  if (t == 0) S[gi] = (sm[0] + sm[1]) + (sm[2] + sm[3]);
}

typedef const __attribute__((address_space(1))) void GAS;
typedef __attribute__((address_space(3))) void LAS;

__device__ __forceinline__ void gload16(const void* g, void* l){
  __builtin_amdgcn_global_load_lds((GAS*)g, (LAS*)l, 16, 0, 0);
}

// ---------------- fallback GEMM (chunked path): 128x128, 1-phase ------------
#define BM 128
#define BN 128
#define BK 64

__global__ __launch_bounds__(256, 3) void gemm_rows(
    const uint16_t* __restrict__ P, const uint16_t* __restrict__ xT,
    const float* __restrict__ S, int row0, float* __restrict__ O)
{
  __shared__ uint16_t smem[16384];      // As[128][64] | Bs[128][64]
  uint16_t* As = smem;
  uint16_t* Bs = smem + 8192;

  const int tid  = threadIdx.x;
  const int lane = tid & 63;
  const int wave = tid >> 6;
  const int wr = (wave >> 1) * 64;
  const int wc = (wave & 1) * 64;
  const int l15 = lane & 15;
  const int lq  = lane >> 4;

  const size_t m0 = (size_t)blockIdx.x * BM;
  const size_t n0 = (size_t)blockIdx.y * BN;

  const int srow = tid >> 3;                    // 0..31
  const int sx   = (tid & 7) ^ (srow & 7);      // swizzled source k-group
  const uint16_t* gA = P  + (m0 + srow) * (size_t)NCOLS + sx * 8;
  const uint16_t* gB = xT + (n0 + srow) * (size_t)NCOLS + sx * 8;

  f32x4 acc[4][4];
  #pragma unroll
  for (int i = 0; i < 4; ++i)
    #pragma unroll
    for (int j = 0; j < 4; ++j)
      #pragma unroll
      for (int q = 0; q < 4; ++q) acc[i][j][q] = 0.0f;

  const int axor = l15 & 7;

  for (int k0 = 0; k0 < NCOLS; k0 += BK){
    #pragma unroll
    for (int r = 0; r < 4; ++r)
      gload16(gA + (size_t)(32 * r) * NCOLS + k0, As + (tid + 256 * r) * 8);
    #pragma unroll
    for (int r = 0; r < 4; ++r)
      gload16(gB + (size_t)(32 * r) * NCOLS + k0, Bs + (tid + 256 * r) * 8);
    __syncthreads();
    #pragma unroll
    for (int ks = 0; ks < 2; ++ks){
      const int kphys = ((lq + 4 * ks) ^ axor) * 8;
      f16x8 af[4], bfrag[4];
      #pragma unroll
      for (int i = 0; i < 4; ++i)
        af[i] = *reinterpret_cast<const f16x8*>(As + (wr + i*16 + l15) * BK + kphys);
      #pragma unroll
      for (int j = 0; j < 4; ++j)
        bfrag[j] = *reinterpret_cast<const f16x8*>(Bs + (wc + j*16 + l15) * BK + kphys);
      #pragma unroll
      for (int i = 0; i < 4; ++i)
        #pragma unroll
        for (int j = 0; j < 4; ++j)
          acc[i][j] = __builtin_amdgcn_mfma_f32_16x16x32_f16(af[i], bfrag[j], acc[i][j], 0, 0, 0);
    }
    __syncthreads();
  }

  #pragma unroll
  for (int i = 0; i < 4; ++i){
    float rinv[4];
    #pragma unroll
    for (int r = 0; r < 4; ++r)
      rinv[r] = 1.0f / S[row0 + m0 + wr + i*16 + lq*4 + r];
    #pragma unroll
    for (int j = 0; j < 4; ++j){
      const size_t col = n0 + wc + j*16 + l15;
      #pragma unroll
      for (int r = 0; r < 4; ++r){
        const size_t row = m0 + wr + i*16 + lq*4 + r;
        O[row * DDIM + col] = acc[i][j][r] * rinv[r];
      }
    }
  }
}

// =========== main GEMM: 256x128, 4-phase interleave, counted vmcnt ==========
// Data paths (staging map, XOR swizzle, frag offsets, XCD mapping, epilogue)
// are IDENTICAL to round-1's verified gemm256 (passed, 0 bank conflicts).
// Only the K-loop schedule changes: per K-tile (BK=64), 4 phases of
// {ds_read subtile || issue 2 staging loads -> s_barrier -> lgkmcnt(0) ->
//  setprio(1) 8xMFMA setprio(0) -> s_barrier}, triple-buffered LDS,
// vmcnt(6) ONCE per K-tile at entry (never 0 in steady state) — the
// T3+T4(+T5) template, which is the documented fix for the ~890 TF ceiling
// the 1-phase structure measured at (155 us = 886 TF, R1).
#define GM 256
#define GN 128
#define GK 64
#define GNT (NCOLS / GK)                 // 128 K-tiles
#define GBUF 24576                       // elems per buffer (A 16384 + B 8192)

__global__ __launch_bounds__(512, 2) void gemm8p(
    const uint16_t* __restrict__ P,      // [8192][8192] f16 (unnormalized E')
    const uint16_t* __restrict__ xT,     // [1024][8192] f16
    const float* __restrict__ S,         // [8192] row sums
    float* __restrict__ O)               // [8192][1024] f32
{
  extern __shared__ uint16_t sm[];       // 3 * 24576 uint16 = 144 KB

  const int tid  = threadIdx.x;
  const int lane = tid & 63;
  const int wave = tid >> 6;             // 0..7
  const int wr = (wave >> 1) * 64;       // 4 m-waves
  const int wc = (wave & 1) * 64;        // 2 n-waves
  const int l15 = lane & 15;
  const int lq  = lane >> 4;             // 0..3
  const int axor = l15 & 7;

  // XCD mapping (R1-verified): XCD x = b&7 owns n-tile x, all 32 m-tiles.
  const int b   = blockIdx.x;
  const int swz = (b & 7) * 32 + (b >> 3);
  const size_t m0 = (size_t)(swz & 31) * GM;    // 32 m-tiles
  const size_t n0 = (size_t)(swz >> 5) * GN;    // 8  n-tiles

  // Staging map (R1-verified): thread t covers LDS chunks t+512r;
  // row=(t>>3)+64r, phys kc8=t&7 holds logical (t&7)^(row&7).
  const int srow = tid >> 3;                    // 0..63
  const int sx   = (tid & 7) ^ (srow & 7);
  const uint16_t* gA = P  + (m0 + srow) * (size_t)NCOLS + sx * 8;
  const uint16_t* gB = xT + (n0 + srow) * (size_t)NCOLS + sx * 8;

  uint16_t* buf0 = sm;
  uint16_t* buf1 = sm + GBUF;
  uint16_t* buf2 = sm + 2 * GBUF;

  // staging pieces (2 gload_lds each; 6 total per K-tile, same bytes as R1)
  auto STAGE_A01 = [&](uint16_t* base, int kt){
    const int kk = kt * GK;
    gload16(gA + kk,                        base + tid * 8);
    gload16(gA + (size_t)64 * NCOLS + kk,   base + (tid + 512) * 8);
  };
  auto STAGE_A23 = [&](uint16_t* base, int kt){
    const int kk = kt * GK;
    gload16(gA + (size_t)128 * NCOLS + kk,  base + (tid + 1024) * 8);
    gload16(gA + (size_t)192 * NCOLS + kk,  base + (tid + 1536) * 8);
  };
  auto STAGE_B = [&](uint16_t* base, int kt){
    const int kk = kt * GK;
    gload16(gB + kk,                        base + 16384 + tid * 8);
    gload16(gB + (size_t)64 * NCOLS + kk,   base + 16384 + (tid + 512) * 8);
  };

  f32x4 acc[4][4];
  #pragma unroll
  for (int i = 0; i < 4; ++i)
    #pragma unroll
    for (int j = 0; j < 4; ++j)
      #pragma unroll
      for (int q = 0; q < 4; ++q) acc[i][j][q] = 0.0f;

  // prologue: tiles 0 and 1 fully staged (12 loads in flight).
  STAGE_A01(buf0, 0); STAGE_A23(buf0, 0); STAGE_B(buf0, 0);
  STAGE_A01(buf1, 1); STAGE_A23(buf1, 1); STAGE_B(buf1, 1);

  uint16_t *pc = buf0, *pn = buf1, *ps = buf2;
  for (int t = 0; t < GNT; ++t){
    // entry: tile t's 6 loads landed; tile t+1's 6 stay in flight.
    if (t + 1 < GNT) asm volatile("s_waitcnt vmcnt(6)" ::: "memory");
    else             asm volatile("s_waitcnt vmcnt(0)" ::: "memory");
    __builtin_amdgcn_s_barrier();

    const bool pre = (t + 2 < GNT);
    f16x8 bf[2][4];                       // B frags cached per ks across h

    #pragma unroll
    for (int ks = 0; ks < 2; ++ks){
      #pragma unroll
      for (int h = 0; h < 2; ++h){
        const int kphys = ((lq + 4 * ks) ^ axor) * 8;
        f16x8 af0 = *reinterpret_cast<const f16x8*>(pc + (wr + (2*h    )*16 + l15) * GK + kphys);
        f16x8 af1 = *reinterpret_cast<const f16x8*>(pc + (wr + (2*h + 1)*16 + l15) * GK + kphys);
        if (h == 0){
          #pragma unroll
          for (int j = 0; j < 4; ++j)
            bf[ks][j] = *reinterpret_cast<const f16x8*>(pc + 16384 + (wc + j*16 + l15) * GK + kphys);
        }
        if (pre){
          if      (ks == 0 && h == 0) STAGE_A01(ps, t + 2);
          else if (ks == 0 && h == 1) STAGE_A23(ps, t + 2);
          else if (ks == 1 && h == 0) STAGE_B  (ps, t + 2);
        }
        __builtin_amdgcn_s_barrier();
        asm volatile("s_waitcnt lgkmcnt(0)" ::: "memory");
        __builtin_amdgcn_s_setprio(1);
        #pragma unroll
        for (int j = 0; j < 4; ++j)
          acc[2*h    ][j] = __builtin_amdgcn_mfma_f32_16x16x32_f16(af0, bf[ks][j], acc[2*h    ][j], 0, 0, 0);
        #pragma unroll
        for (int j = 0; j < 4; ++j)
          acc[2*h + 1][j] = __builtin_amdgcn_mfma_f32_16x16x32_f16(af1, bf[ks][j], acc[2*h + 1][j], 0, 0, 0);
        __builtin_amdgcn_s_setprio(0);
        __builtin_amdgcn_s_barrier();
      }
    }
    uint16_t* tmp = pc; pc = pn; pn = ps; ps = tmp;
  }

  // epilogue (R1-verified C/D mapping): col=lane&15, row=quad*4+reg.
  #pragma unroll
  for (int i = 0; i < 4; ++i){
    float rinv[4];
    #pragma unroll
    for (int r = 0; r < 4; ++r)
      rinv[r] = 1.0f / S[m0 + wr + i*16 + lq*4 + r];
    #pragma unroll
    for (int j = 0; j < 4; ++j){
      const size_t col = n0 + wc + j*16 + l15;
      #pragma unroll
      for (int r = 0; r < 4; ++r){
        const size_t row = m0 + wr + i*16 + lq*4 + r;
        O[row * DDIM + col] = acc[i][j][r] * rinv[r];
      }
    }
  }
}

// ---------------------------------------------------------------------------
extern "C" void kernel_launch(void* const* d_in, const int* in_sizes, int n_in,
                              void* d_out, int out_size, void* d_ws, size_t ws_size,
                              hipStream_t stream)
{
  (void)in_sizes; (void)n_in; (void)out_size;
  const float* x = (const float*)d_in[0];       // [8192][1024] f32; d_in[1] unused
  float* O = (float*)d_out;                     // [8192][1024] f32
  uint8_t* ws = (uint8_t*)d_ws;

  // layout: S[8192] f32 | xT (16.8 MB) | P (134 MB)
  float* S = (float*)ws;
  const size_t S_bytes = (size_t)NROWS * sizeof(float);
  uint16_t* xT = (uint16_t*)(ws + S_bytes);
  const size_t xT_bytes = (size_t)DDIM * NROWS * sizeof(uint16_t);
  uint16_t* P = (uint16_t*)(ws + S_bytes + xT_bytes);
  const size_t used = S_bytes + xT_bytes;
  const size_t avail = ws_size > used ? ws_size - used : 0;

  const size_t fullP = (size_t)NROWS * NCOLS * sizeof(uint16_t); // 134 MB
  if (avail >= fullP){
    gen_trans_rows<<<NROWS, 256, 0, stream>>>(x, xT, P, S);
    gemm8p<<<256, 512, 3 * GBUF * sizeof(uint16_t), stream>>>(P, xT, S, O);
  } else {
    transpose_cast<<<dim3(DDIM/32, NROWS/32), 256, 0, stream>>>(x, xT);
    int R = 128;
    for (int r = 4096; r >= 128; r >>= 1)
      if ((size_t)r * NCOLS * sizeof(uint16_t) <= avail){ R = r; break; }
    for (int r0 = 0; r0 < NROWS; r0 += R){
      gen_rows<<<R, 256, 0, stream>>>(P, S, r0);
      gemm_rows<<<dim3(R/BM, DDIM/BN), 256, 0, stream>>>(P, xT, S, r0, O + (size_t)r0 * DDIM);
    }
  }
}